// Round 15
// baseline (374.741 us; speedup 1.0000x reference)
//
#include <hip/hip_runtime.h>
#include <hip/hip_bf16.h>

// GATv2 x2 + BN + pool + MLP for MI355X. Round 15: tail round (conv1 frozen
// at ~107us; tail=263us over 13 launches).
// (1) csr_build: hist+scan+scatter fused into ONE 64-block persistent kernel
//     with device-scope atomic barriers (replaces 3 kernels + removes the
//     single-block scan stall).
// (2) gemm: XCD-aware block swizzle (l&7 -> contiguous m-range per XCD) so
//     A-slabs are fetched once per XCD, not 8x round-robin.
// (3) convert_x + convert_w fused into one launch (P=1 path).

__device__ __forceinline__ float lrelu(float x, float s) { return x > 0.f ? x : s * x; }

typedef _Float16 half8 __attribute__((ext_vector_type(8)));
typedef _Float16 half4v __attribute__((ext_vector_type(4)));
typedef _Float16 half2v __attribute__((ext_vector_type(2)));
typedef float f32x4 __attribute__((ext_vector_type(4)));

#define GLOBAL_AS __attribute__((address_space(1)))
#define LDS_AS __attribute__((address_space(3)))

__device__ __forceinline__ void async_copy16(const void* g, void* l) {
  __builtin_amdgcn_global_load_lds((const GLOBAL_AS unsigned int*)g,
                                   (LDS_AS unsigned int*)l, 16, 0, 0);
}

__global__ void zero_ints(int* __restrict__ p, int n) {
  const int t = blockIdx.x * blockDim.x + threadIdx.x;
  if (t < n) p[t] = 0;
}

// ---------------- fused CSR build: hist + scan + scatter -------------------
// 64 co-resident blocks (1/CU at most), device-scope atomic barriers.
__device__ __forceinline__ void gbar(int* ctr, int nb) {
  __syncthreads();
  if (threadIdx.x == 0) {
    __threadfence();
    atomicAdd(ctr, 1);
    while (atomicAdd(ctr, 0) < nb) {
    }
    __threadfence();
  }
  __syncthreads();
}

__global__ __launch_bounds__(1024) void csr_build(const int* __restrict__ ei, int E, int N,
                                                  int* __restrict__ counts,
                                                  int* __restrict__ row_ptr,
                                                  int* __restrict__ cursor,
                                                  int* __restrict__ col,
                                                  int* __restrict__ bars,
                                                  int* __restrict__ bsum) {
  const int nb = gridDim.x;  // 64
  const int b = blockIdx.x, t = threadIdx.x;
  const int ET = E + N;
  // phase 1: histogram (counts pre-zeroed by zero_ints)
  for (int i = b * 1024 + t; i < ET; i += nb * 1024) {
    const int dst = (i < E) ? ei[E + i] : (i - E);
    atomicAdd(&counts[dst], 1);
  }
  gbar(&bars[0], nb);
  // phase 2: per-block chunk sums (chunk <= 1024)
  const int chunk = (N + nb - 1) / nb;
  const int c0 = min(N, b * chunk), c1 = min(N, c0 + chunk);
  const int n_loc = c1 - c0;
  __shared__ int sv[1024];
  __shared__ int sred[16];
  __shared__ int soff;
  const int myv = (t < n_loc) ? counts[c0 + t] : 0;
  sv[t] = myv;
  int r = myv;
#pragma unroll
  for (int off = 32; off; off >>= 1) r += __shfl_down(r, off);
  if ((t & 63) == 0) sred[t >> 6] = r;
  __syncthreads();
  if (t == 0) {
    int s = 0;
    for (int w = 0; w < 16; ++w) s += sred[w];
    bsum[b] = s;
  }
  gbar(&bars[1], nb);
  // phase 3: block offset (redundant per-block reduce of bsum[0..b)), then
  // LDS inclusive scan of the chunk -> exclusive row_ptr/cursor.
  if (t < 64) {
    int v = (t < b) ? bsum[t] : 0;
#pragma unroll
    for (int off = 32; off; off >>= 1) v += __shfl_down(v, off);
    if (t == 0) soff = v;
  }
  __syncthreads();
  for (int off = 1; off < n_loc; off <<= 1) {
    const int add = (t >= off && t < n_loc) ? sv[t - off] : 0;
    __syncthreads();
    if (t < n_loc) sv[t] += add;
    __syncthreads();
  }
  if (t < n_loc) {
    const int excl = soff + sv[t] - myv;
    row_ptr[c0 + t] = excl;
    cursor[c0 + t] = excl;
  }
  if (b == nb - 1 && t == 0) row_ptr[N] = soff + bsum[b];
  gbar(&bars[2], nb);
  // phase 4: scatter
  for (int i = b * 1024 + t; i < ET; i += nb * 1024) {
    const int dst = (i < E) ? ei[E + i] : (i - E);
    const int src = (i < E) ? ei[i] : (i - E);
    const int pos = atomicAdd(&cursor[dst], 1);
    col[pos] = src;
  }
}

// ---------------- f16 conversions (scale x16, hi only) ----------------
__device__ __forceinline__ void convert_x_body(const float* __restrict__ x,
                                               _Float16* __restrict__ A2,
                                               int t, int M) {
  if (t >= M * 64) return;
  const int m = t >> 6;
  const int k4 = (t & 63) * 4;
  const float4 v = *(const float4*)(x + (size_t)m * 256 + k4);
  const float sx = 16.f;
  *(half4v*)(A2 + (size_t)m * 256 + k4) =
      (half4v){(_Float16)(v.x * sx), (_Float16)(v.y * sx),
               (_Float16)(v.z * sx), (_Float16)(v.w * sx)};
}

__device__ __forceinline__ void convert_w_body(const float* __restrict__ wl,
                                               const float* __restrict__ wr,
                                               _Float16* __restrict__ B2,
                                               int n, int k, int colOff, int W) {
  const float v = 16.f * ((n < W) ? wl[k * 1024 + colOff + n]
                                  : wr[k * 1024 + colOff + (n - W)]);
  B2[(size_t)n * 256 + k] = (_Float16)v;
}

// Fused (P=1): blocks [0,nxb) convert x; blocks [nxb, nxb+2W) convert w.
__global__ __launch_bounds__(256) void convert_xw(const float* __restrict__ x,
                                                  const float* __restrict__ wl,
                                                  const float* __restrict__ wr,
                                                  _Float16* __restrict__ A2,
                                                  _Float16* __restrict__ B2,
                                                  int M, int colOff, int W, int nxb) {
  if ((int)blockIdx.x < nxb) {
    convert_x_body(x, A2, blockIdx.x * 256 + threadIdx.x, M);
  } else {
    convert_w_body(wl, wr, B2, blockIdx.x - nxb, threadIdx.x, colOff, W);
  }
}

__global__ void convert_x(const float* __restrict__ x, _Float16* __restrict__ A2, int M) {
  convert_x_body(x, A2, blockIdx.x * blockDim.x + threadIdx.x, M);
}

__global__ __launch_bounds__(256) void convert_w(const float* __restrict__ wl,
                                                 const float* __restrict__ wr,
                                                 _Float16* __restrict__ B2,
                                                 int colOff, int W) {
  convert_w_body(wl, wr, B2, blockIdx.x, threadIdx.x, colOff, W);
}

// ---- MFMA GEMM: xlr[M x Ntot] (f16) = (A_hi @ B_hi^T) / 256, K=256 --------
// XCD-aware swizzle: linear block id l -> xcd = l&7 owns a contiguous
// m-range, so each XCD's L2 fetches each A-slab once (not 8x round-robin).
__global__ __launch_bounds__(256) void gemm_mfma(const _Float16* __restrict__ A2,
                                                 const _Float16* __restrict__ B2,
                                                 _Float16* __restrict__ C,
                                                 int M, int Ntot) {
  __shared__ __align__(16) _Float16 LDSbuf[2 * 128 * 64];  // As | Bs ; reused by epilogue
  _Float16* As = LDSbuf;
  _Float16* Bs = LDSbuf + 128 * 64;
  const int nt = gridDim.x;            // n-tiles
  const int mt = (M + 127) >> 7;       // m-tiles
  const int mchunk = (mt + 7) >> 3;    // m-tiles per XCD
  const int l = blockIdx.y * nt + blockIdx.x;
  const int k = l >> 3;
  const int yt = (l & 7) * mchunk + k / nt;
  if (yt >= mt) return;
  const int xt = k % nt;
  const int tid = threadIdx.x;
  const int lane = tid & 63;
  const int wv = tid >> 6;
  const int wm = wv & 1, wn = wv >> 1;
  const int m_blk = yt * 128;
  const int n_blk = xt * 128;
  const int row16 = lane & 15, quad = lane >> 4;
  f32x4 acc[4][4] = {};

  for (int kt = 0; kt < 4; ++kt) {
    const int kg = kt * 64;
#pragma unroll
    for (int j = 0; j < 4; ++j) {
      const int ci = j * 256 + tid;
      const int row = ci >> 3;
      const int c = ci & 7;
      const int gc = c ^ (row & 7);
      _Float16* ldsA = &As[(j * 256 + wv * 64) * 8];
      _Float16* ldsB = &Bs[(j * 256 + wv * 64) * 8];
      const int growA = min(m_blk + row, M - 1);
      async_copy16(A2 + (size_t)growA * 256 + kg + gc * 8, ldsA);
      async_copy16(B2 + (size_t)(n_blk + row) * 256 + kg + gc * 8, ldsB);
    }
    __syncthreads();
#pragma unroll
    for (int ks = 0; ks < 2; ++ks) {
      half8 af[4], bf[4];
#pragma unroll
      for (int mi = 0; mi < 4; ++mi) {
        const int r = wm * 64 + mi * 16 + row16;
        const int cl = (ks * 4 + quad) ^ (r & 7);
        af[mi] = *(const half8*)&As[r * 64 + cl * 8];
      }
#pragma unroll
      for (int ni = 0; ni < 4; ++ni) {
        const int r = wn * 64 + ni * 16 + row16;
        const int cl = (ks * 4 + quad) ^ (r & 7);
        bf[ni] = *(const half8*)&Bs[r * 64 + cl * 8];
      }
#pragma unroll
      for (int mi = 0; mi < 4; ++mi)
#pragma unroll
        for (int ni = 0; ni < 4; ++ni)
          acc[mi][ni] = __builtin_amdgcn_mfma_f32_16x16x32_f16(af[mi], bf[ni], acc[mi][ni], 0, 0, 0);
    }
    __syncthreads();  // also frees LDSbuf for the epilogue after last kt
  }
  // Epilogue: each wave stages its 64x64 f16 tile in LDS -> coalesced half8.
  const float inv = 1.f / 256.f;
  _Float16* tw = LDSbuf + wv * 4096;
#pragma unroll
  for (int mi = 0; mi < 4; ++mi)
#pragma unroll
    for (int reg = 0; reg < 4; ++reg) {
      const int r_in = mi * 16 + quad * 4 + reg;
#pragma unroll
      for (int ni = 0; ni < 4; ++ni)
        tw[r_in * 64 + ni * 16 + row16] = (_Float16)(acc[mi][ni][reg] * inv);
    }
#pragma unroll
  for (int p8 = 0; p8 < 8; ++p8) {
    const int row = p8 * 8 + (lane >> 3);
    const int grow = m_blk + wm * 64 + row;
    if (grow < M) {
      const half8 v = *(const half8*)&tw[row * 64 + (lane & 7) * 8];
      *(half8*)(C + (size_t)grow * Ntot + n_blk + wn * 64 + (lane & 7) * 8) = v;
    }
  }
}

// ---- conv1 attention, W=1024: HALF-NODE PER WAVE (2 waves/node) -----------
__global__ __launch_bounds__(256, 8) void conv1_attn_hw(const _Float16* __restrict__ xlrp,
                                                        const int* __restrict__ row_ptr,
                                                        const int* __restrict__ col,
                                                        const float* __restrict__ att,
                                                        const float* __restrict__ bias,
                                                        _Float16* __restrict__ h1, int N) {
  union H8 { half8 v; half2v p[4]; };
  const int wv = threadIdx.x >> 6;
  const int lane = threadIdx.x & 63;
  const int i = blockIdx.x * 2 + (wv >> 1);
  if (i >= N) return;
  const int f = (wv & 1) * 512 + lane * 8;  // channel base within [0,1024)
  half2v a2[4], xr2[4];
  float acc[8];
#pragma unroll
  for (int p = 0; p < 4; ++p)
    a2[p] = (half2v){(_Float16)att[f + 2 * p], (_Float16)att[f + 2 * p + 1]};
  {
    H8 u;
    u.v = *(const half8*)(xlrp + (size_t)i * 2048 + 1024 + f);
#pragma unroll
    for (int k = 0; k < 4; ++k) xr2[k] = u.p[k];
  }
#pragma unroll
  for (int c = 0; c < 8; ++c) acc[c] = 0.f;
  float m = -3.0e38f, l = 0.f;
  const int kb = row_ptr[i];
  const int ke = row_ptr[i + 1];
  for (int base = kb; base < ke; base += 64) {
    const int cnt = min(64, ke - base);
    const int myc = (lane < cnt) ? col[base + lane] : 0;
    H8 xc, xn;
    {
      const int s0 = __shfl(myc, 0);
      xc.v = *(const half8*)(xlrp + (size_t)s0 * 2048 + f);
    }
    for (int q = 0; q < cnt; ++q) {
      if (q + 1 < cnt) {
        const int sn = __shfl(myc, q + 1);
        xn.v = *(const half8*)(xlrp + (size_t)sn * 2048 + f);
      }
      float s = 0.f;
#pragma unroll
      for (int p = 0; p < 4; ++p) {
        const half2v xp = xc.p[p];
        const half2v t = xp + xr2[p];
        const half2v t5 = t * (half2v){(_Float16)0.2f, (_Float16)0.2f};
        const half2v lr = __builtin_elementwise_max(t, t5);
        s = __builtin_amdgcn_fdot2(a2[p], lr, s, false);
      }
      // reduce across the 16-lane head group
      s += __shfl_xor(s, 8);
      s += __shfl_xor(s, 4);
      s += __shfl_xor(s, 2);
      s += __shfl_xor(s, 1);
      if (s <= m) {  // common: running max unchanged, no rescale
        const float pw = __expf(s - m);
        l += pw;
#pragma unroll
        for (int p = 0; p < 4; ++p) {
          const half2v xp = xc.p[p];
          acc[2 * p] += pw * (float)xp[0];  // v_fma_mix_f32
          acc[2 * p + 1] += pw * (float)xp[1];
        }
      } else {
        const float sc = __expf(m - s);
        m = s;
        l = l * sc + 1.f;
#pragma unroll
        for (int p = 0; p < 4; ++p) {
          const half2v xp = xc.p[p];
          acc[2 * p] = acc[2 * p] * sc + (float)xp[0];
          acc[2 * p + 1] = acc[2 * p + 1] * sc + (float)xp[1];
        }
      }
      xc = xn;
    }
  }
  const float inv = 1.f / (l + 1e-16f);
  H8 u;
#pragma unroll
  for (int k = 0; k < 4; ++k) {
    const int c = 2 * k;
    u.p[k] = (half2v){(_Float16)(acc[c] * inv + bias[f + c]),
                      (_Float16)(acc[c + 1] * inv + bias[f + c + 1])};
  }
  *(half8*)(h1 + (size_t)i * 1024 + f) = u.v;
}

// ---- conv1 attention fallback (P>1, W<1024): one node per wave ------------
template <int CPT>
__global__ __launch_bounds__(256, 6) void conv1_attn(const _Float16* __restrict__ xlrp,
                                                     const int* __restrict__ row_ptr,
                                                     const int* __restrict__ col,
                                                     const float* __restrict__ att,
                                                     const float* __restrict__ bias,
                                                     _Float16* __restrict__ h1,
                                                     int W, int N) {
  constexpr int PAIRS = CPT / 2;
  constexpr int NV8 = CPT / 8;
  constexpr int HG = 128 / CPT;
  union H8 { half8 v; half2v p[4]; };
  const int lane = threadIdx.x & 63;
  const int i = blockIdx.x * 4 + (threadIdx.x >> 6);
  if (i >= N) return;
  const int f = lane * CPT;
  half2v a2[PAIRS], xr2[PAIRS];
  float acc[CPT];
#pragma unroll
  for (int p = 0; p < PAIRS; ++p)
    a2[p] = (half2v){(_Float16)att[f + 2 * p], (_Float16)att[f + 2 * p + 1]};
  {
    const half8* xrp = (const half8*)(xlrp + (size_t)i * (2 * W) + W + f);
#pragma unroll
    for (int j = 0; j < NV8; ++j) {
      H8 u; u.v = xrp[j];
#pragma unroll
      for (int k = 0; k < 4; ++k) xr2[j * 4 + k] = u.p[k];
    }
  }
#pragma unroll
  for (int c = 0; c < CPT; ++c) acc[c] = 0.f;
  float m = -3.0e38f, l = 0.f;
  const int kb = row_ptr[i];
  const int ke = row_ptr[i + 1];
  for (int base = kb; base < ke; base += 64) {
    const int cnt = min(64, ke - base);
    const int myc = (lane < cnt) ? col[base + lane] : 0;
    H8 xc[NV8], xn[NV8];
    {
      const int s0 = __shfl(myc, 0);
      const half8* rp = (const half8*)(xlrp + (size_t)s0 * (2 * W) + f);
#pragma unroll
      for (int j = 0; j < NV8; ++j) xc[j].v = rp[j];
    }
    for (int q = 0; q < cnt; ++q) {
      if (q + 1 < cnt) {
        const int sn = __shfl(myc, q + 1);
        const half8* rp = (const half8*)(xlrp + (size_t)sn * (2 * W) + f);
#pragma unroll
        for (int j = 0; j < NV8; ++j) xn[j].v = rp[j];
      }
      float s = 0.f;
#pragma unroll
      for (int p = 0; p < PAIRS; ++p) {
        const half2v xp = xc[p >> 2].p[p & 3];
        const half2v t = xp + xr2[p];
        const half2v t5 = t * (half2v){(_Float16)0.2f, (_Float16)0.2f};
        const half2v lr = __builtin_elementwise_max(t, t5);
        s = __builtin_amdgcn_fdot2(a2[p], lr, s, false);
      }
#pragma unroll
      for (int off = HG / 2; off >= 1; off >>= 1) s += __shfl_xor(s, off);
      if (s <= m) {
        const float pw = __expf(s - m);
        l += pw;
#pragma unroll
        for (int p = 0; p < PAIRS; ++p) {
          const half2v xp = xc[p >> 2].p[p & 3];
          acc[2 * p] += pw * (float)xp[0];
          acc[2 * p + 1] += pw * (float)xp[1];
        }
      } else {
        const float sc = __expf(m - s);
        m = s;
        l = l * sc + 1.f;
#pragma unroll
        for (int p = 0; p < PAIRS; ++p) {
          const half2v xp = xc[p >> 2].p[p & 3];
          acc[2 * p] = acc[2 * p] * sc + (float)xp[0];
          acc[2 * p + 1] = acc[2 * p + 1] * sc + (float)xp[1];
        }
      }
#pragma unroll
      for (int j = 0; j < NV8; ++j) xc[j] = xn[j];
    }
  }
  const float inv = 1.f / (l + 1e-16f);
  _Float16* outp = h1 + (size_t)i * 1024 + f;
#pragma unroll
  for (int j = 0; j < NV8; ++j) {
    H8 u;
#pragma unroll
    for (int k = 0; k < 4; ++k) {
      const int c = j * 8 + 2 * k;
      u.p[k] = (half2v){(_Float16)(acc[c] * inv + bias[f + c]),
                        (_Float16)(acc[c + 1] * inv + bias[f + c + 1])};
    }
    ((half8*)outp)[j] = u.v;
  }
}

// ------- BN1 stats: 256 partial blocks, NO atomics -------------------------
__global__ __launch_bounds__(256) void bn1_stats(const _Float16* __restrict__ h1,
                                                 float* __restrict__ part, int N) {
  const int f = threadIdx.x * 4;  // 0..1020
  const int y = blockIdx.y;       // 0..255
  const int chunk = (N + 255) / 256;
  const int r0 = y * chunk;
  const int r1 = min(N, r0 + chunk);
  float s0 = 0.f, s1 = 0.f, s2 = 0.f, s3 = 0.f;
  float q0 = 0.f, q1 = 0.f, q2 = 0.f, q3 = 0.f;
  for (int r = r0; r < r1; ++r) {
    const half4v v4 = *(const half4v*)(h1 + (size_t)r * 1024 + f);
    const float v0 = (float)v4[0], v1 = (float)v4[1], v2 = (float)v4[2], v3 = (float)v4[3];
    s0 += v0; q0 += v0 * v0;
    s1 += v1; q1 += v1 * v1;
    s2 += v2; q2 += v2 * v2;
    s3 += v3; q3 += v3 * v3;
  }
  float* ps = part + (size_t)y * 1024 + f;
  ps[0] = s0; ps[1] = s1; ps[2] = s2; ps[3] = s3;
  float* pq = part + 262144 + (size_t)y * 1024 + f;
  pq[0] = q0; pq[1] = q1; pq[2] = q2; pq[3] = q3;
}

// ------- BN1 finalize: reduce partials, precompute scale/shift -------------
__global__ __launch_bounds__(256) void bn1_final(const float* __restrict__ part,
                                                 const float* __restrict__ g1,
                                                 const float* __restrict__ be1,
                                                 float* __restrict__ scale1,
                                                 float* __restrict__ shift1, int N) {
  const int c = blockIdx.x * 256 + threadIdx.x;  // 0..1023
  float s = 0.f, q = 0.f;
  for (int y = 0; y < 256; ++y) {
    s += part[(size_t)y * 1024 + c];
    q += part[262144 + (size_t)y * 1024 + c];
  }
  const float invN = 1.f / (float)N;
  const float mu = s * invN;
  const float var = q * invN - mu * mu;
  const float rs = 1.f / sqrtf(var + 1e-5f);
  const float sc = rs * g1[c];
  scale1[c] = sc;
  shift1[c] = be1[c] - mu * sc;
}

// ---- BN1 apply + lrelu + conv2 projections: one block per node ------------
__global__ __launch_bounds__(256) void bn1_proj(const _Float16* __restrict__ h1,
                                                const float* __restrict__ scale1,
                                                const float* __restrict__ shift1,
                                                const float* __restrict__ w2l,
                                                const float* __restrict__ w2r,
                                                float* __restrict__ xl2,
                                                float* __restrict__ xr2, int N) {
  const int i = blockIdx.x;
  const int tid = threadIdx.x;
  const int f = tid * 4;
  const half4v hv = *(const half4v*)(h1 + (size_t)i * 1024 + f);
  const float4 sc4 = *(const float4*)(scale1 + f);
  const float4 sh4 = *(const float4*)(shift1 + f);
  const float4 wl = *(const float4*)(w2l + f);
  const float4 wr = *(const float4*)(w2r + f);
  float pl = 0.f, pr = 0.f;
  {
    float v;
    v = lrelu((float)hv[0] * sc4.x + sh4.x, 0.01f); pl += v * wl.x; pr += v * wr.x;
    v = lrelu((float)hv[1] * sc4.y + sh4.y, 0.01f); pl += v * wl.y; pr += v * wr.y;
    v = lrelu((float)hv[2] * sc4.z + sh4.z, 0.01f); pl += v * wl.z; pr += v * wr.z;
    v = lrelu((float)hv[3] * sc4.w + sh4.w, 0.01f); pl += v * wl.w; pr += v * wr.w;
  }
#pragma unroll
  for (int off = 32; off; off >>= 1) {
    pl += __shfl_down(pl, off);
    pr += __shfl_down(pr, off);
  }
  __shared__ float sp[8];
  if ((tid & 63) == 0) {
    sp[tid >> 6] = pl;
    sp[4 + (tid >> 6)] = pr;
  }
  __syncthreads();
  if (tid == 0) {
    xl2[i] = sp[0] + sp[1] + sp[2] + sp[3];
    xr2[i] = sp[4] + sp[5] + sp[6] + sp[7];
  }
}

// ------- conv2 attention + fused BN2 stats (block reduce + 2 atomics) ------
__global__ __launch_bounds__(256) void conv2_attn(const float* __restrict__ xl2,
                                                  const float* __restrict__ xr2,
                                                  const int* __restrict__ row_ptr,
                                                  const int* __restrict__ col,
                                                  const float* __restrict__ att2,
                                                  const float* __restrict__ b2,
                                                  float* __restrict__ out2,
                                                  float* __restrict__ bn2acc, int N) {
  const int i = blockIdx.x * blockDim.x + threadIdx.x;
  float val = 0.f;
  if (i < N) {
    const float a = att2[0];
    const float xr = xr2[i];
    float m = -3.0e38f, l = 0.f, acc = 0.f;
    const int kb = row_ptr[i];
    const int ke = row_ptr[i + 1];
    for (int k = kb; k < ke; ++k) {
      const float xv = xl2[col[k]];
      const float s = a * lrelu(xv + xr, 0.2f);
      const float mn = fmaxf(m, s);
      const float sc = __expf(m - mn);
      const float p = __expf(s - mn);
      l = l * sc + p;
      acc = acc * sc + p * xv;
      m = mn;
    }
    val = acc / (l + 1e-16f) + b2[0];
    out2[i] = val;
  }
  float s = (i < N) ? val : 0.f;
  float q = s * s;
#pragma unroll
  for (int off = 32; off; off >>= 1) {
    s += __shfl_down(s, off);
    q += __shfl_down(q, off);
  }
  __shared__ float red[8];
  if ((threadIdx.x & 63) == 0) {
    red[threadIdx.x >> 6] = s;
    red[4 + (threadIdx.x >> 6)] = q;
  }
  __syncthreads();
  if (threadIdx.x == 0) {
    atomicAdd(&bn2acc[0], red[0] + red[1] + red[2] + red[3]);
    atomicAdd(&bn2acc[1], red[4] + red[5] + red[6] + red[7]);
  }
}

// -------- BN2 apply + lrelu + graph mean pool (LDS pre-reduction) ---------
__global__ __launch_bounds__(256) void bn2_pool(const float* __restrict__ out2,
                                                const float* __restrict__ bn2acc,
                                                const float* __restrict__ g2,
                                                const float* __restrict__ be2,
                                                const int* __restrict__ batch,
                                                float* __restrict__ pool_sum,
                                                float* __restrict__ pool_cnt, int N) {
  __shared__ float ls[64];
  __shared__ float lc[64];
  const int tid = threadIdx.x;
  if (tid < 64) { ls[tid] = 0.f; lc[tid] = 0.f; }
  __syncthreads();
  const int i = blockIdx.x * blockDim.x + tid;
  if (i < N) {
    const float invN = 1.f / (float)N;
    const float mu = bn2acc[0] * invN;
    const float var = bn2acc[1] * invN - mu * mu;
    const float rs = 1.f / sqrtf(var + 1e-5f);
    const float v = lrelu((out2[i] - mu) * rs * g2[0] + be2[0], 0.01f);
    const int g = batch[i];
    atomicAdd(&ls[g], v);
    atomicAdd(&lc[g], 1.f);
  }
  __syncthreads();
  if (tid < 64 && lc[tid] != 0.f) {
    atomicAdd(&pool_sum[tid], ls[tid]);
    atomicAdd(&pool_cnt[tid], lc[tid]);
  }
}

// ---------------- MLP head ----------------
__global__ void head_mlp(const float* __restrict__ pool_sum, const float* __restrict__ pool_cnt,
                         const float* __restrict__ lw1, const float* __restrict__ lb1,
                         const float* __restrict__ lw2, const float* __restrict__ lb2,
                         float* __restrict__ out) {
  const int g = threadIdx.x;
  if (g >= 64) return;
  const float p = pool_sum[g] / fmaxf(pool_cnt[g], 1.f);
  float acc = 0.f;
  for (int d = 0; d < 128; ++d) {
    float t = p * lw1[d] + lb1[d];
    t = lrelu(t, 0.01f);
    acc += t * lw2[d];
  }
  out[g] = acc + lb2[0];
}

extern "C" void kernel_launch(void* const* d_in, const int* in_sizes, int n_in,
                              void* d_out, int out_size, void* d_ws, size_t ws_size,
                              hipStream_t stream) {
  const float* x = (const float*)d_in[0];
  const int* ei = (const int*)d_in[1];
  const int* batch = (const int*)d_in[2];
  const float* w1_l = (const float*)d_in[3];
  const float* w1_r = (const float*)d_in[4];
  const float* att1 = (const float*)d_in[5];
  const float* b1 = (const float*)d_in[6];
  const float* g1 = (const float*)d_in[7];
  const float* be1 = (const float*)d_in[8];
  const float* w2_l = (const float*)d_in[9];
  const float* w2_r = (const float*)d_in[10];
  const float* att2 = (const float*)d_in[11];
  const float* b2 = (const float*)d_in[12];
  const float* g2 = (const float*)d_in[13];
  const float* be2 = (const float*)d_in[14];
  const float* lw1 = (const float*)d_in[15];
  const float* lb1 = (const float*)d_in[16];
  const float* lw2 = (const float*)d_in[17];
  const float* lb2 = (const float*)d_in[18];

  const int N = in_sizes[2];
  const int E = in_sizes[1] / 2;
  const int ET = E + N;

  const size_t AL = 255;
  auto al = [&](size_t b) { return (b + AL) & ~AL; };
  // zbase: counts[N] | bars(32B)+bsum(256B) hole | bn2acc | pool_sum | pool_cnt
  const size_t zbytes = (size_t)N * 4 + 4096 + 4096 + 16 + 256 + 256;
  const size_t fixedNoXlr = al((size_t)N * 2048)     // h1 (f16)
                          + 3 * al((size_t)N * 4)    // xl2, xr2, out2
                          + al((size_t)(N + 1) * 4)  // row_ptr
                          + al((size_t)ET * 4)       // col
                          + al((size_t)N * 4)        // cursor
                          + al(zbytes)
                          + al((size_t)524288 * 4)   // bn1_part
                          + 2 * al(4096);            // bn1_scale, bn1_shift
  const size_t a2b = al((size_t)N * 256 * 2);
  int P = 1;
  while (P < 8) {
    const size_t xlrb = al((size_t)N * (4096 / P));  // f16
    const size_t b2b = al((size_t)(2 * (1024 / P)) * 256 * 2);
    const size_t extra = (P == 1) ? 0 : (a2b + b2b);
    if (fixedNoXlr + xlrb + extra <= ws_size) break;
    P <<= 1;
  }
  const int W = 1024 / P;

  char* ws = (char*)d_ws;
  size_t off = 0;
  auto alloc = [&](size_t b) { size_t p = off; off += al(b); return p; };
  _Float16* h1 = (_Float16*)(ws + alloc((size_t)N * 2048));
  _Float16* xlrp = (_Float16*)(ws + alloc((size_t)N * (4096 / P)));
  float* xl2 = (float*)(ws + alloc((size_t)N * 4));
  float* xr2 = (float*)(ws + alloc((size_t)N * 4));
  float* out2 = (float*)(ws + alloc((size_t)N * 4));
  int* row_ptr = (int*)(ws + alloc((size_t)(N + 1) * 4));
  int* colb = (int*)(ws + alloc((size_t)ET * 4));
  int* cursor = (int*)(ws + alloc((size_t)N * 4));
  char* zbase = ws + alloc(zbytes);
  int* counts = (int*)zbase;
  int* bars = (int*)(zbase + (size_t)N * 4);          // 3 ints (zeroed)
  int* bsum = (int*)(zbase + (size_t)N * 4 + 128);    // 64 ints
  float* bn2acc = (float*)(zbase + (size_t)N * 4 + 8192);
  float* pool_sum = (float*)(zbase + (size_t)N * 4 + 8192 + 16);
  float* pool_cnt = (float*)(zbase + (size_t)N * 4 + 8192 + 16 + 256);
  float* bn1_part = (float*)(ws + alloc((size_t)524288 * 4));
  float* bn1_scale = (float*)(ws + alloc(4096));
  float* bn1_shift = (float*)(ws + alloc(4096));

  _Float16 *A2, *B2;
  if (P == 1) {  // h1 (41MB f16) dead until conv1_attn: A2 (10.25) + B2 (1) fit
    A2 = (_Float16*)h1;
    B2 = (_Float16*)((char*)h1 + a2b);
  } else {
    A2 = (_Float16*)(ws + alloc((size_t)N * 256 * 2));
    B2 = (_Float16*)(ws + alloc((size_t)(2 * W) * 256 * 2));
  }

  const int zn = (int)(zbytes / 4);
  zero_ints<<<(zn + 255) / 256, 256, 0, stream>>>((int*)zbase, zn);

  // fused CSR build: 64 co-resident blocks (chunk = ceil(N/64) must be <=1024)
  csr_build<<<64, 1024, 0, stream>>>(ei, E, N, counts, row_ptr, cursor, colb, bars, bsum);

  const int nxb = (N * 64 + 255) / 256;
  if (P == 1) {
    convert_xw<<<nxb + 2 * W, 256, 0, stream>>>(x, w1_l, w1_r, A2, B2, N, 0, W, nxb);
  } else {
    convert_x<<<nxb, 256, 0, stream>>>(x, A2, N);
  }
  for (int p = 0; p < P; ++p) {
    if (P > 1) convert_w<<<2 * W, 256, 0, stream>>>(w1_l, w1_r, B2, p * W, W);
    const int nt = 2 * W / 128;
    const int mt = (N + 127) / 128;
    const int mchunk = (mt + 7) / 8;
    gemm_mfma<<<dim3(nt, 8 * mchunk), 256, 0, stream>>>(A2, B2, xlrp, N, 2 * W);
    if (W >= 1024)
      conv1_attn_hw<<<(N + 1) / 2, 256, 0, stream>>>(xlrp, row_ptr, colb,
                                                     att1, b1, h1, N);
    else
      conv1_attn<8><<<(N + 3) / 4, 256, 0, stream>>>(xlrp, row_ptr, colb,
                                                     att1 + p * W, b1 + p * W,
                                                     h1 + p * W, W, N);
  }

  bn1_stats<<<dim3(1, 256), 256, 0, stream>>>(h1, bn1_part, N);
  bn1_final<<<4, 256, 0, stream>>>(bn1_part, g1, be1, bn1_scale, bn1_shift, N);
  bn1_proj<<<N, 256, 0, stream>>>(h1, bn1_scale, bn1_shift, w2_l, w2_r, xl2, xr2, N);
  conv2_attn<<<(N + 255) / 256, 256, 0, stream>>>(xl2, xr2, row_ptr, colb, att2, b2,
                                                  out2, bn2acc, N);
  bn2_pool<<<(N + 255) / 256, 256, 0, stream>>>(out2, bn2acc, g2, be2, batch, pool_sum, pool_cnt, N);
  head_mlp<<<1, 64, 0, stream>>>(pool_sum, pool_cnt, lw1, lb1, lw2, lb2, (float*)d_out);
}

// Round 16
// 361.871 us; speedup vs baseline: 1.0356x; 1.0356x over previous
//
#include <hip/hip_runtime.h>
#include <hip/hip_bf16.h>

// GATv2 x2 + BN + pool + MLP for MI355X. Round 16: surgical revert of R15's
// fused csr_build (64 persistent blocks cut the random-atomic scatter's
// memory parallelism 5x -> +5us net). Back to R14's hist/scan/scatter trio.
// KEPT from R15: convert_xw fusion (-1 launch), XCD-swizzled gemm.

__device__ __forceinline__ float lrelu(float x, float s) { return x > 0.f ? x : s * x; }

typedef _Float16 half8 __attribute__((ext_vector_type(8)));
typedef _Float16 half4v __attribute__((ext_vector_type(4)));
typedef _Float16 half2v __attribute__((ext_vector_type(2)));
typedef float f32x4 __attribute__((ext_vector_type(4)));

#define GLOBAL_AS __attribute__((address_space(1)))
#define LDS_AS __attribute__((address_space(3)))

__device__ __forceinline__ void async_copy16(const void* g, void* l) {
  __builtin_amdgcn_global_load_lds((const GLOBAL_AS unsigned int*)g,
                                   (LDS_AS unsigned int*)l, 16, 0, 0);
}

__global__ void zero_ints(int* __restrict__ p, int n) {
  const int t = blockIdx.x * blockDim.x + threadIdx.x;
  if (t < n) p[t] = 0;
}

// ---------------- CSR build (by dst, self-loops appended) ----------------
__global__ void edge_hist(const int* __restrict__ ei, int E, int N,
                          int* __restrict__ counts) {
  const int t = blockIdx.x * blockDim.x + threadIdx.x;
  if (t >= E + N) return;
  const int dst = (t < E) ? ei[E + t] : (t - E);
  atomicAdd(&counts[dst], 1);
}

__global__ __launch_bounds__(1024) void scan_counts(const int* __restrict__ counts,
                                                    int* __restrict__ row_ptr,
                                                    int* __restrict__ cursor, int N) {
  __shared__ int sdata[1024];
  __shared__ int lcnt[20480];  // 80 KB: fits N=20000
  const int t = threadIdx.x;
  if (N <= 20480) {
    for (int j = t; j < N; j += 1024) lcnt[j] = counts[j];  // coalesced
    __syncthreads();
    const int chunk = (N + 1023) / 1024;
    const int s0 = min(N, t * chunk);
    const int s1 = min(N, s0 + chunk);
    int lsum = 0;
    for (int i = s0; i < s1; ++i) lsum += lcnt[i];
    sdata[t] = lsum;
    __syncthreads();
    for (int off = 1; off < 1024; off <<= 1) {
      int v = 0;
      if (t >= off) v = sdata[t - off];
      __syncthreads();
      sdata[t] += v;
      __syncthreads();
    }
    int run = sdata[t] - lsum;
    for (int i = s0; i < s1; ++i) { const int c = lcnt[i]; lcnt[i] = run; run += c; }
    if (s0 < N && s1 == N) row_ptr[N] = run;
    __syncthreads();
    for (int j = t; j < N; j += 1024) {  // coalesced
      const int v = lcnt[j];
      row_ptr[j] = v;
      cursor[j] = v;
    }
  } else {  // fallback: global path
    const int chunk = (N + 1023) / 1024;
    const int s0 = min(N, t * chunk);
    const int s1 = min(N, s0 + chunk);
    int lsum = 0;
    for (int i = s0; i < s1; ++i) lsum += counts[i];
    sdata[t] = lsum;
    __syncthreads();
    for (int off = 1; off < 1024; off <<= 1) {
      int v = 0;
      if (t >= off) v = sdata[t - off];
      __syncthreads();
      sdata[t] += v;
      __syncthreads();
    }
    int run = sdata[t] - lsum;
    for (int i = s0; i < s1; ++i) {
      row_ptr[i] = run;
      cursor[i] = run;
      run += counts[i];
    }
    if (s0 < N && s1 == N) row_ptr[N] = run;
  }
}

__global__ void edge_scatter(const int* __restrict__ ei, int E, int N,
                             int* __restrict__ cursor, int* __restrict__ col) {
  const int t = blockIdx.x * blockDim.x + threadIdx.x;
  if (t >= E + N) return;
  const int dst = (t < E) ? ei[E + t] : (t - E);
  const int src = (t < E) ? ei[t] : (t - E);
  const int pos = atomicAdd(&cursor[dst], 1);
  col[pos] = src;
}

// ---------------- f16 conversions (scale x16, hi only) ----------------
__device__ __forceinline__ void convert_x_body(const float* __restrict__ x,
                                               _Float16* __restrict__ A2,
                                               int t, int M) {
  if (t >= M * 64) return;
  const int m = t >> 6;
  const int k4 = (t & 63) * 4;
  const float4 v = *(const float4*)(x + (size_t)m * 256 + k4);
  const float sx = 16.f;
  *(half4v*)(A2 + (size_t)m * 256 + k4) =
      (half4v){(_Float16)(v.x * sx), (_Float16)(v.y * sx),
               (_Float16)(v.z * sx), (_Float16)(v.w * sx)};
}

__device__ __forceinline__ void convert_w_body(const float* __restrict__ wl,
                                               const float* __restrict__ wr,
                                               _Float16* __restrict__ B2,
                                               int n, int k, int colOff, int W) {
  const float v = 16.f * ((n < W) ? wl[k * 1024 + colOff + n]
                                  : wr[k * 1024 + colOff + (n - W)]);
  B2[(size_t)n * 256 + k] = (_Float16)v;
}

// Fused (P=1): blocks [0,nxb) convert x; blocks [nxb, nxb+2W) convert w.
__global__ __launch_bounds__(256) void convert_xw(const float* __restrict__ x,
                                                  const float* __restrict__ wl,
                                                  const float* __restrict__ wr,
                                                  _Float16* __restrict__ A2,
                                                  _Float16* __restrict__ B2,
                                                  int M, int colOff, int W, int nxb) {
  if ((int)blockIdx.x < nxb) {
    convert_x_body(x, A2, blockIdx.x * 256 + threadIdx.x, M);
  } else {
    convert_w_body(wl, wr, B2, blockIdx.x - nxb, threadIdx.x, colOff, W);
  }
}

__global__ void convert_x(const float* __restrict__ x, _Float16* __restrict__ A2, int M) {
  convert_x_body(x, A2, blockIdx.x * blockDim.x + threadIdx.x, M);
}

__global__ __launch_bounds__(256) void convert_w(const float* __restrict__ wl,
                                                 const float* __restrict__ wr,
                                                 _Float16* __restrict__ B2,
                                                 int colOff, int W) {
  convert_w_body(wl, wr, B2, blockIdx.x, threadIdx.x, colOff, W);
}

// ---- MFMA GEMM: xlr[M x Ntot] (f16) = (A_hi @ B_hi^T) / 256, K=256 --------
// XCD-aware swizzle: l&7 -> contiguous m-range per XCD (A-slab L2 locality).
__global__ __launch_bounds__(256) void gemm_mfma(const _Float16* __restrict__ A2,
                                                 const _Float16* __restrict__ B2,
                                                 _Float16* __restrict__ C,
                                                 int M, int Ntot) {
  __shared__ __align__(16) _Float16 LDSbuf[2 * 128 * 64];  // As | Bs ; reused by epilogue
  _Float16* As = LDSbuf;
  _Float16* Bs = LDSbuf + 128 * 64;
  const int nt = gridDim.x;            // n-tiles
  const int mt = (M + 127) >> 7;       // m-tiles
  const int mchunk = (mt + 7) >> 3;    // m-tiles per XCD
  const int l = blockIdx.y * nt + blockIdx.x;
  const int k = l >> 3;
  const int yt = (l & 7) * mchunk + k / nt;
  if (yt >= mt) return;
  const int xt = k % nt;
  const int tid = threadIdx.x;
  const int lane = tid & 63;
  const int wv = tid >> 6;
  const int wm = wv & 1, wn = wv >> 1;
  const int m_blk = yt * 128;
  const int n_blk = xt * 128;
  const int row16 = lane & 15, quad = lane >> 4;
  f32x4 acc[4][4] = {};

  for (int kt = 0; kt < 4; ++kt) {
    const int kg = kt * 64;
#pragma unroll
    for (int j = 0; j < 4; ++j) {
      const int ci = j * 256 + tid;
      const int row = ci >> 3;
      const int c = ci & 7;
      const int gc = c ^ (row & 7);
      _Float16* ldsA = &As[(j * 256 + wv * 64) * 8];
      _Float16* ldsB = &Bs[(j * 256 + wv * 64) * 8];
      const int growA = min(m_blk + row, M - 1);
      async_copy16(A2 + (size_t)growA * 256 + kg + gc * 8, ldsA);
      async_copy16(B2 + (size_t)(n_blk + row) * 256 + kg + gc * 8, ldsB);
    }
    __syncthreads();
#pragma unroll
    for (int ks = 0; ks < 2; ++ks) {
      half8 af[4], bf[4];
#pragma unroll
      for (int mi = 0; mi < 4; ++mi) {
        const int r = wm * 64 + mi * 16 + row16;
        const int cl = (ks * 4 + quad) ^ (r & 7);
        af[mi] = *(const half8*)&As[r * 64 + cl * 8];
      }
#pragma unroll
      for (int ni = 0; ni < 4; ++ni) {
        const int r = wn * 64 + ni * 16 + row16;
        const int cl = (ks * 4 + quad) ^ (r & 7);
        bf[ni] = *(const half8*)&Bs[r * 64 + cl * 8];
      }
#pragma unroll
      for (int mi = 0; mi < 4; ++mi)
#pragma unroll
        for (int ni = 0; ni < 4; ++ni)
          acc[mi][ni] = __builtin_amdgcn_mfma_f32_16x16x32_f16(af[mi], bf[ni], acc[mi][ni], 0, 0, 0);
    }
    __syncthreads();  // also frees LDSbuf for the epilogue after last kt
  }
  // Epilogue: each wave stages its 64x64 f16 tile in LDS -> coalesced half8.
  const float inv = 1.f / 256.f;
  _Float16* tw = LDSbuf + wv * 4096;
#pragma unroll
  for (int mi = 0; mi < 4; ++mi)
#pragma unroll
    for (int reg = 0; reg < 4; ++reg) {
      const int r_in = mi * 16 + quad * 4 + reg;
#pragma unroll
      for (int ni = 0; ni < 4; ++ni)
        tw[r_in * 64 + ni * 16 + row16] = (_Float16)(acc[mi][ni][reg] * inv);
    }
#pragma unroll
  for (int p8 = 0; p8 < 8; ++p8) {
    const int row = p8 * 8 + (lane >> 3);
    const int grow = m_blk + wm * 64 + row;
    if (grow < M) {
      const half8 v = *(const half8*)&tw[row * 64 + (lane & 7) * 8];
      *(half8*)(C + (size_t)grow * Ntot + n_blk + wn * 64 + (lane & 7) * 8) = v;
    }
  }
}

// ---- conv1 attention, W=1024: HALF-NODE PER WAVE (2 waves/node) -----------
__global__ __launch_bounds__(256, 8) void conv1_attn_hw(const _Float16* __restrict__ xlrp,
                                                        const int* __restrict__ row_ptr,
                                                        const int* __restrict__ col,
                                                        const float* __restrict__ att,
                                                        const float* __restrict__ bias,
                                                        _Float16* __restrict__ h1, int N) {
  union H8 { half8 v; half2v p[4]; };
  const int wv = threadIdx.x >> 6;
  const int lane = threadIdx.x & 63;
  const int i = blockIdx.x * 2 + (wv >> 1);
  if (i >= N) return;
  const int f = (wv & 1) * 512 + lane * 8;  // channel base within [0,1024)
  half2v a2[4], xr2[4];
  float acc[8];
#pragma unroll
  for (int p = 0; p < 4; ++p)
    a2[p] = (half2v){(_Float16)att[f + 2 * p], (_Float16)att[f + 2 * p + 1]};
  {
    H8 u;
    u.v = *(const half8*)(xlrp + (size_t)i * 2048 + 1024 + f);
#pragma unroll
    for (int k = 0; k < 4; ++k) xr2[k] = u.p[k];
  }
#pragma unroll
  for (int c = 0; c < 8; ++c) acc[c] = 0.f;
  float m = -3.0e38f, l = 0.f;
  const int kb = row_ptr[i];
  const int ke = row_ptr[i + 1];
  for (int base = kb; base < ke; base += 64) {
    const int cnt = min(64, ke - base);
    const int myc = (lane < cnt) ? col[base + lane] : 0;
    H8 xc, xn;
    {
      const int s0 = __shfl(myc, 0);
      xc.v = *(const half8*)(xlrp + (size_t)s0 * 2048 + f);
    }
    for (int q = 0; q < cnt; ++q) {
      if (q + 1 < cnt) {
        const int sn = __shfl(myc, q + 1);
        xn.v = *(const half8*)(xlrp + (size_t)sn * 2048 + f);
      }
      float s = 0.f;
#pragma unroll
      for (int p = 0; p < 4; ++p) {
        const half2v xp = xc.p[p];
        const half2v t = xp + xr2[p];
        const half2v t5 = t * (half2v){(_Float16)0.2f, (_Float16)0.2f};
        const half2v lr = __builtin_elementwise_max(t, t5);
        s = __builtin_amdgcn_fdot2(a2[p], lr, s, false);
      }
      // reduce across the 16-lane head group
      s += __shfl_xor(s, 8);
      s += __shfl_xor(s, 4);
      s += __shfl_xor(s, 2);
      s += __shfl_xor(s, 1);
      if (s <= m) {  // common: running max unchanged, no rescale
        const float pw = __expf(s - m);
        l += pw;
#pragma unroll
        for (int p = 0; p < 4; ++p) {
          const half2v xp = xc.p[p];
          acc[2 * p] += pw * (float)xp[0];  // v_fma_mix_f32
          acc[2 * p + 1] += pw * (float)xp[1];
        }
      } else {
        const float sc = __expf(m - s);
        m = s;
        l = l * sc + 1.f;
#pragma unroll
        for (int p = 0; p < 4; ++p) {
          const half2v xp = xc.p[p];
          acc[2 * p] = acc[2 * p] * sc + (float)xp[0];
          acc[2 * p + 1] = acc[2 * p + 1] * sc + (float)xp[1];
        }
      }
      xc = xn;
    }
  }
  const float inv = 1.f / (l + 1e-16f);
  H8 u;
#pragma unroll
  for (int k = 0; k < 4; ++k) {
    const int c = 2 * k;
    u.p[k] = (half2v){(_Float16)(acc[c] * inv + bias[f + c]),
                      (_Float16)(acc[c + 1] * inv + bias[f + c + 1])};
  }
  *(half8*)(h1 + (size_t)i * 1024 + f) = u.v;
}

// ---- conv1 attention fallback (P>1, W<1024): one node per wave ------------
template <int CPT>
__global__ __launch_bounds__(256, 6) void conv1_attn(const _Float16* __restrict__ xlrp,
                                                     const int* __restrict__ row_ptr,
                                                     const int* __restrict__ col,
                                                     const float* __restrict__ att,
                                                     const float* __restrict__ bias,
                                                     _Float16* __restrict__ h1,
                                                     int W, int N) {
  constexpr int PAIRS = CPT / 2;
  constexpr int NV8 = CPT / 8;
  constexpr int HG = 128 / CPT;
  union H8 { half8 v; half2v p[4]; };
  const int lane = threadIdx.x & 63;
  const int i = blockIdx.x * 4 + (threadIdx.x >> 6);
  if (i >= N) return;
  const int f = lane * CPT;
  half2v a2[PAIRS], xr2[PAIRS];
  float acc[CPT];
#pragma unroll
  for (int p = 0; p < PAIRS; ++p)
    a2[p] = (half2v){(_Float16)att[f + 2 * p], (_Float16)att[f + 2 * p + 1]};
  {
    const half8* xrp = (const half8*)(xlrp + (size_t)i * (2 * W) + W + f);
#pragma unroll
    for (int j = 0; j < NV8; ++j) {
      H8 u; u.v = xrp[j];
#pragma unroll
      for (int k = 0; k < 4; ++k) xr2[j * 4 + k] = u.p[k];
    }
  }
#pragma unroll
  for (int c = 0; c < CPT; ++c) acc[c] = 0.f;
  float m = -3.0e38f, l = 0.f;
  const int kb = row_ptr[i];
  const int ke = row_ptr[i + 1];
  for (int base = kb; base < ke; base += 64) {
    const int cnt = min(64, ke - base);
    const int myc = (lane < cnt) ? col[base + lane] : 0;
    H8 xc[NV8], xn[NV8];
    {
      const int s0 = __shfl(myc, 0);
      const half8* rp = (const half8*)(xlrp + (size_t)s0 * (2 * W) + f);
#pragma unroll
      for (int j = 0; j < NV8; ++j) xc[j].v = rp[j];
    }
    for (int q = 0; q < cnt; ++q) {
      if (q + 1 < cnt) {
        const int sn = __shfl(myc, q + 1);
        const half8* rp = (const half8*)(xlrp + (size_t)sn * (2 * W) + f);
#pragma unroll
        for (int j = 0; j < NV8; ++j) xn[j].v = rp[j];
      }
      float s = 0.f;
#pragma unroll
      for (int p = 0; p < PAIRS; ++p) {
        const half2v xp = xc[p >> 2].p[p & 3];
        const half2v t = xp + xr2[p];
        const half2v t5 = t * (half2v){(_Float16)0.2f, (_Float16)0.2f};
        const half2v lr = __builtin_elementwise_max(t, t5);
        s = __builtin_amdgcn_fdot2(a2[p], lr, s, false);
      }
#pragma unroll
      for (int off = HG / 2; off >= 1; off >>= 1) s += __shfl_xor(s, off);
      if (s <= m) {
        const float pw = __expf(s - m);
        l += pw;
#pragma unroll
        for (int p = 0; p < PAIRS; ++p) {
          const half2v xp = xc[p >> 2].p[p & 3];
          acc[2 * p] += pw * (float)xp[0];
          acc[2 * p + 1] += pw * (float)xp[1];
        }
      } else {
        const float sc = __expf(m - s);
        m = s;
        l = l * sc + 1.f;
#pragma unroll
        for (int p = 0; p < PAIRS; ++p) {
          const half2v xp = xc[p >> 2].p[p & 3];
          acc[2 * p] = acc[2 * p] * sc + (float)xp[0];
          acc[2 * p + 1] = acc[2 * p + 1] * sc + (float)xp[1];
        }
      }
#pragma unroll
      for (int j = 0; j < NV8; ++j) xc[j] = xn[j];
    }
  }
  const float inv = 1.f / (l + 1e-16f);
  _Float16* outp = h1 + (size_t)i * 1024 + f;
#pragma unroll
  for (int j = 0; j < NV8; ++j) {
    H8 u;
#pragma unroll
    for (int k = 0; k < 4; ++k) {
      const int c = j * 8 + 2 * k;
      u.p[k] = (half2v){(_Float16)(acc[c] * inv + bias[f + c]),
                        (_Float16)(acc[c + 1] * inv + bias[f + c + 1])};
    }
    ((half8*)outp)[j] = u.v;
  }
}

// ------- BN1 stats: 256 partial blocks, NO atomics -------------------------
__global__ __launch_bounds__(256) void bn1_stats(const _Float16* __restrict__ h1,
                                                 float* __restrict__ part, int N) {
  const int f = threadIdx.x * 4;  // 0..1020
  const int y = blockIdx.y;       // 0..255
  const int chunk = (N + 255) / 256;
  const int r0 = y * chunk;
  const int r1 = min(N, r0 + chunk);
  float s0 = 0.f, s1 = 0.f, s2 = 0.f, s3 = 0.f;
  float q0 = 0.f, q1 = 0.f, q2 = 0.f, q3 = 0.f;
  for (int r = r0; r < r1; ++r) {
    const half4v v4 = *(const half4v*)(h1 + (size_t)r * 1024 + f);
    const float v0 = (float)v4[0], v1 = (float)v4[1], v2 = (float)v4[2], v3 = (float)v4[3];
    s0 += v0; q0 += v0 * v0;
    s1 += v1; q1 += v1 * v1;
    s2 += v2; q2 += v2 * v2;
    s3 += v3; q3 += v3 * v3;
  }
  float* ps = part + (size_t)y * 1024 + f;
  ps[0] = s0; ps[1] = s1; ps[2] = s2; ps[3] = s3;
  float* pq = part + 262144 + (size_t)y * 1024 + f;
  pq[0] = q0; pq[1] = q1; pq[2] = q2; pq[3] = q3;
}

// ------- BN1 finalize: reduce partials, precompute scale/shift -------------
__global__ __launch_bounds__(256) void bn1_final(const float* __restrict__ part,
                                                 const float* __restrict__ g1,
                                                 const float* __restrict__ be1,
                                                 float* __restrict__ scale1,
                                                 float* __restrict__ shift1, int N) {
  const int c = blockIdx.x * 256 + threadIdx.x;  // 0..1023
  float s = 0.f, q = 0.f;
  for (int y = 0; y < 256; ++y) {
    s += part[(size_t)y * 1024 + c];
    q += part[262144 + (size_t)y * 1024 + c];
  }
  const float invN = 1.f / (float)N;
  const float mu = s * invN;
  const float var = q * invN - mu * mu;
  const float rs = 1.f / sqrtf(var + 1e-5f);
  const float sc = rs * g1[c];
  scale1[c] = sc;
  shift1[c] = be1[c] - mu * sc;
}

// ---- BN1 apply + lrelu + conv2 projections: one block per node ------------
__global__ __launch_bounds__(256) void bn1_proj(const _Float16* __restrict__ h1,
                                                const float* __restrict__ scale1,
                                                const float* __restrict__ shift1,
                                                const float* __restrict__ w2l,
                                                const float* __restrict__ w2r,
                                                float* __restrict__ xl2,
                                                float* __restrict__ xr2, int N) {
  const int i = blockIdx.x;
  const int tid = threadIdx.x;
  const int f = tid * 4;
  const half4v hv = *(const half4v*)(h1 + (size_t)i * 1024 + f);
  const float4 sc4 = *(const float4*)(scale1 + f);
  const float4 sh4 = *(const float4*)(shift1 + f);
  const float4 wl = *(const float4*)(w2l + f);
  const float4 wr = *(const float4*)(w2r + f);
  float pl = 0.f, pr = 0.f;
  {
    float v;
    v = lrelu((float)hv[0] * sc4.x + sh4.x, 0.01f); pl += v * wl.x; pr += v * wr.x;
    v = lrelu((float)hv[1] * sc4.y + sh4.y, 0.01f); pl += v * wl.y; pr += v * wr.y;
    v = lrelu((float)hv[2] * sc4.z + sh4.z, 0.01f); pl += v * wl.z; pr += v * wr.z;
    v = lrelu((float)hv[3] * sc4.w + sh4.w, 0.01f); pl += v * wl.w; pr += v * wr.w;
  }
#pragma unroll
  for (int off = 32; off; off >>= 1) {
    pl += __shfl_down(pl, off);
    pr += __shfl_down(pr, off);
  }
  __shared__ float sp[8];
  if ((tid & 63) == 0) {
    sp[tid >> 6] = pl;
    sp[4 + (tid >> 6)] = pr;
  }
  __syncthreads();
  if (tid == 0) {
    xl2[i] = sp[0] + sp[1] + sp[2] + sp[3];
    xr2[i] = sp[4] + sp[5] + sp[6] + sp[7];
  }
}

// ------- conv2 attention + fused BN2 stats (block reduce + 2 atomics) ------
__global__ __launch_bounds__(256) void conv2_attn(const float* __restrict__ xl2,
                                                  const float* __restrict__ xr2,
                                                  const int* __restrict__ row_ptr,
                                                  const int* __restrict__ col,
                                                  const float* __restrict__ att2,
                                                  const float* __restrict__ b2,
                                                  float* __restrict__ out2,
                                                  float* __restrict__ bn2acc, int N) {
  const int i = blockIdx.x * blockDim.x + threadIdx.x;
  float val = 0.f;
  if (i < N) {
    const float a = att2[0];
    const float xr = xr2[i];
    float m = -3.0e38f, l = 0.f, acc = 0.f;
    const int kb = row_ptr[i];
    const int ke = row_ptr[i + 1];
    for (int k = kb; k < ke; ++k) {
      const float xv = xl2[col[k]];
      const float s = a * lrelu(xv + xr, 0.2f);
      const float mn = fmaxf(m, s);
      const float sc = __expf(m - mn);
      const float p = __expf(s - mn);
      l = l * sc + p;
      acc = acc * sc + p * xv;
      m = mn;
    }
    val = acc / (l + 1e-16f) + b2[0];
    out2[i] = val;
  }
  float s = (i < N) ? val : 0.f;
  float q = s * s;
#pragma unroll
  for (int off = 32; off; off >>= 1) {
    s += __shfl_down(s, off);
    q += __shfl_down(q, off);
  }
  __shared__ float red[8];
  if ((threadIdx.x & 63) == 0) {
    red[threadIdx.x >> 6] = s;
    red[4 + (threadIdx.x >> 6)] = q;
  }
  __syncthreads();
  if (threadIdx.x == 0) {
    atomicAdd(&bn2acc[0], red[0] + red[1] + red[2] + red[3]);
    atomicAdd(&bn2acc[1], red[4] + red[5] + red[6] + red[7]);
  }
}

// -------- BN2 apply + lrelu + graph mean pool (LDS pre-reduction) ---------
__global__ __launch_bounds__(256) void bn2_pool(const float* __restrict__ out2,
                                                const float* __restrict__ bn2acc,
                                                const float* __restrict__ g2,
                                                const float* __restrict__ be2,
                                                const int* __restrict__ batch,
                                                float* __restrict__ pool_sum,
                                                float* __restrict__ pool_cnt, int N) {
  __shared__ float ls[64];
  __shared__ float lc[64];
  const int tid = threadIdx.x;
  if (tid < 64) { ls[tid] = 0.f; lc[tid] = 0.f; }
  __syncthreads();
  const int i = blockIdx.x * blockDim.x + tid;
  if (i < N) {
    const float invN = 1.f / (float)N;
    const float mu = bn2acc[0] * invN;
    const float var = bn2acc[1] * invN - mu * mu;
    const float rs = 1.f / sqrtf(var + 1e-5f);
    const float v = lrelu((out2[i] - mu) * rs * g2[0] + be2[0], 0.01f);
    const int g = batch[i];
    atomicAdd(&ls[g], v);
    atomicAdd(&lc[g], 1.f);
  }
  __syncthreads();
  if (tid < 64 && lc[tid] != 0.f) {
    atomicAdd(&pool_sum[tid], ls[tid]);
    atomicAdd(&pool_cnt[tid], lc[tid]);
  }
}

// ---------------- MLP head ----------------
__global__ void head_mlp(const float* __restrict__ pool_sum, const float* __restrict__ pool_cnt,
                         const float* __restrict__ lw1, const float* __restrict__ lb1,
                         const float* __restrict__ lw2, const float* __restrict__ lb2,
                         float* __restrict__ out) {
  const int g = threadIdx.x;
  if (g >= 64) return;
  const float p = pool_sum[g] / fmaxf(pool_cnt[g], 1.f);
  float acc = 0.f;
  for (int d = 0; d < 128; ++d) {
    float t = p * lw1[d] + lb1[d];
    t = lrelu(t, 0.01f);
    acc += t * lw2[d];
  }
  out[g] = acc + lb2[0];
}

extern "C" void kernel_launch(void* const* d_in, const int* in_sizes, int n_in,
                              void* d_out, int out_size, void* d_ws, size_t ws_size,
                              hipStream_t stream) {
  const float* x = (const float*)d_in[0];
  const int* ei = (const int*)d_in[1];
  const int* batch = (const int*)d_in[2];
  const float* w1_l = (const float*)d_in[3];
  const float* w1_r = (const float*)d_in[4];
  const float* att1 = (const float*)d_in[5];
  const float* b1 = (const float*)d_in[6];
  const float* g1 = (const float*)d_in[7];
  const float* be1 = (const float*)d_in[8];
  const float* w2_l = (const float*)d_in[9];
  const float* w2_r = (const float*)d_in[10];
  const float* att2 = (const float*)d_in[11];
  const float* b2 = (const float*)d_in[12];
  const float* g2 = (const float*)d_in[13];
  const float* be2 = (const float*)d_in[14];
  const float* lw1 = (const float*)d_in[15];
  const float* lb1 = (const float*)d_in[16];
  const float* lw2 = (const float*)d_in[17];
  const float* lb2 = (const float*)d_in[18];

  const int N = in_sizes[2];
  const int E = in_sizes[1] / 2;
  const int ET = E + N;

  const size_t AL = 255;
  auto al = [&](size_t b) { return (b + AL) & ~AL; };
  const size_t zbytes = (size_t)N * 4 + 4096 + 4096 + 16 + 256 + 256;
  const size_t fixedNoXlr = al((size_t)N * 2048)     // h1 (f16)
                          + 3 * al((size_t)N * 4)    // xl2, xr2, out2
                          + al((size_t)(N + 1) * 4)  // row_ptr
                          + al((size_t)ET * 4)       // col
                          + al((size_t)N * 4)        // cursor
                          + al(zbytes)
                          + al((size_t)524288 * 4)   // bn1_part
                          + 2 * al(4096);            // bn1_scale, bn1_shift
  const size_t a2b = al((size_t)N * 256 * 2);
  int P = 1;
  while (P < 8) {
    const size_t xlrb = al((size_t)N * (4096 / P));  // f16
    const size_t b2b = al((size_t)(2 * (1024 / P)) * 256 * 2);
    const size_t extra = (P == 1) ? 0 : (a2b + b2b);
    if (fixedNoXlr + xlrb + extra <= ws_size) break;
    P <<= 1;
  }
  const int W = 1024 / P;

  char* ws = (char*)d_ws;
  size_t off = 0;
  auto alloc = [&](size_t b) { size_t p = off; off += al(b); return p; };
  _Float16* h1 = (_Float16*)(ws + alloc((size_t)N * 2048));
  _Float16* xlrp = (_Float16*)(ws + alloc((size_t)N * (4096 / P)));
  float* xl2 = (float*)(ws + alloc((size_t)N * 4));
  float* xr2 = (float*)(ws + alloc((size_t)N * 4));
  float* out2 = (float*)(ws + alloc((size_t)N * 4));
  int* row_ptr = (int*)(ws + alloc((size_t)(N + 1) * 4));
  int* colb = (int*)(ws + alloc((size_t)ET * 4));
  int* cursor = (int*)(ws + alloc((size_t)N * 4));
  char* zbase = ws + alloc(zbytes);
  int* counts = (int*)zbase;
  float* bn2acc = (float*)(zbase + (size_t)N * 4 + 8192);
  float* pool_sum = (float*)(zbase + (size_t)N * 4 + 8192 + 16);
  float* pool_cnt = (float*)(zbase + (size_t)N * 4 + 8192 + 16 + 256);
  float* bn1_part = (float*)(ws + alloc((size_t)524288 * 4));
  float* bn1_scale = (float*)(ws + alloc(4096));
  float* bn1_shift = (float*)(ws + alloc(4096));

  _Float16 *A2, *B2;
  if (P == 1) {  // h1 (41MB f16) dead until conv1_attn: A2 (10.25) + B2 (1) fit
    A2 = (_Float16*)h1;
    B2 = (_Float16*)((char*)h1 + a2b);
  } else {
    A2 = (_Float16*)(ws + alloc((size_t)N * 256 * 2));
    B2 = (_Float16*)(ws + alloc((size_t)(2 * W) * 256 * 2));
  }

  const int zn = (int)(zbytes / 4);
  zero_ints<<<(zn + 255) / 256, 256, 0, stream>>>((int*)zbase, zn);

  edge_hist<<<(ET + 255) / 256, 256, 0, stream>>>(ei, E, N, counts);
  scan_counts<<<1, 1024, 0, stream>>>(counts, row_ptr, cursor, N);
  edge_scatter<<<(ET + 255) / 256, 256, 0, stream>>>(ei, E, N, cursor, colb);

  const int nxb = (N * 64 + 255) / 256;
  if (P == 1) {
    convert_xw<<<nxb + 2 * W, 256, 0, stream>>>(x, w1_l, w1_r, A2, B2, N, 0, W, nxb);
  } else {
    convert_x<<<nxb, 256, 0, stream>>>(x, A2, N);
  }
  for (int p = 0; p < P; ++p) {
    if (P > 1) convert_w<<<2 * W, 256, 0, stream>>>(w1_l, w1_r, B2, p * W, W);
    const int nt = 2 * W / 128;
    const int mt = (N + 127) / 128;
    const int mchunk = (mt + 7) / 8;
    gemm_mfma<<<dim3(nt, 8 * mchunk), 256, 0, stream>>>(A2, B2, xlrp, N, 2 * W);
    if (W >= 1024)
      conv1_attn_hw<<<(N + 1) / 2, 256, 0, stream>>>(xlrp, row_ptr, colb,
                                                     att1, b1, h1, N);
    else
      conv1_attn<8><<<(N + 3) / 4, 256, 0, stream>>>(xlrp, row_ptr, colb,
                                                     att1 + p * W, b1 + p * W,
                                                     h1 + p * W, W, N);
  }

  bn1_stats<<<dim3(1, 256), 256, 0, stream>>>(h1, bn1_part, N);
  bn1_final<<<4, 256, 0, stream>>>(bn1_part, g1, be1, bn1_scale, bn1_shift, N);
  bn1_proj<<<N, 256, 0, stream>>>(h1, bn1_scale, bn1_shift, w2_l, w2_r, xl2, xr2, N);
  conv2_attn<<<(N + 255) / 256, 256, 0, stream>>>(xl2, xr2, row_ptr, colb, att2, b2,
                                                  out2, bn2acc, N);
  bn2_pool<<<(N + 255) / 256, 256, 0, stream>>>(out2, bn2acc, g2, be2, batch, pool_sum, pool_cnt, N);
  head_mlp<<<1, 64, 0, stream>>>(pool_sum, pool_cnt, lw1, lb1, lw2, lb2, (float*)d_out);
}